// Round 1
// baseline (228.133 us; speedup 1.0000x reference)
//
#include <hip/hip_runtime.h>

// ContrastiveLoss: B=8192, D=128, T=0.1, SINGLE_POS=False.
// Classes c = 2*tt + tp in {0..3}; pos class = c^1, neg class = c^2.
// loss = -(1/B) * sum_i [valid_i * (Lpos_i*10 - pos_cnt_i*log(Epos_i+Eneg_i)) / pos_cnt_i]
// where Epos/Eneg = masked exp(sim/T) row sums, Lpos = masked sim row sum.

#define NB 8192
#define ND 128
#define TEMP_INV 10.0f
#define LOG2E 1.4426950408889634f

typedef __attribute__((ext_vector_type(8))) short short8;
typedef __attribute__((ext_vector_type(4))) float f32x4;

// ws layout (bytes)
#define OFF_G      0          // 8192*128 bf16 = 2 MB
#define OFF_EPOS   2097152    // 8192 f32
#define OFF_ENEG   2129920    // 8192 f32
#define OFF_LSUM   2162688    // 8192 f32
#define OFF_CLS    2195456    // 8192 u8
#define OFF_CNT    2203648    // 4 i32
#define ZERO_BEG   OFF_EPOS
#define ZERO_SZ    (2203664 - OFF_EPOS)

__device__ __forceinline__ unsigned short f2bf(float x) {
    unsigned int u = __float_as_uint(x);
    unsigned int r = (u + 0x7FFFu + ((u >> 16) & 1u)) >> 16;  // RNE
    return (unsigned short)r;
}

__device__ __forceinline__ float fast_exp2(float x) {
#if __has_builtin(__builtin_amdgcn_exp2f)
    return __builtin_amdgcn_exp2f(x);
#else
    return exp2f(x);
#endif
}

// One block (1 wave) per row: compute norm, write bf16 normalized row,
// class byte, and class histogram.
__global__ __launch_bounds__(64) void prep_kernel(
    const float* __restrict__ F, const int* __restrict__ dix,
    const int* __restrict__ tt, const int* __restrict__ tp,
    unsigned short* __restrict__ G, unsigned char* __restrict__ cls,
    int* __restrict__ cnt)
{
    const int row = blockIdx.x;
    const int lane = threadIdx.x;
    const float2 v = *(const float2*)(F + row * ND + lane * 2);
    float ss = v.x * v.x + v.y * v.y;
    #pragma unroll
    for (int m = 1; m < 64; m <<= 1) ss += __shfl_xor(ss, m, 64);
    const float inv = rsqrtf(fmaxf(ss, 1e-24f));
    ushort2 st;
    st.x = f2bf(v.x * inv);
    st.y = f2bf(v.y * inv);
    *(ushort2*)(G + row * ND + lane * 2) = st;
    if (lane == 0) {
        const int ix = dix[row];
        const int c = ((tt[ix] & 1) << 1) | (tp[ix] & 1);
        cls[row] = (unsigned char)c;
        atomicAdd(&cnt[c], 1);
    }
}

// Grid: 1024 blocks = 256 i-tiles (32 rows each) x 4 j-quarters (2048 cols each).
// Block = 256 threads = 4 waves; wave w handles j-tiles jt ≡ w (mod 4) in quarter.
// A-fragments (wave's 32 rows x 128 k, bf16) live in registers the whole kernel.
// B-fragments are loaded straight from L2 (G is 2 MB, cache-resident). No LDS.
__global__ __launch_bounds__(256) void sim_kernel(
    const unsigned short* __restrict__ G,
    const unsigned char* __restrict__ cls,
    float* __restrict__ EposG, float* __restrict__ EnegG,
    float* __restrict__ LsumG)
{
    const int ib   = blockIdx.x & 255;
    const int jb   = blockIdx.x >> 8;     // 0..3
    const int wave = threadIdx.x >> 6;
    const int lane = threadIdx.x & 63;
    const int q    = lane >> 4;           // quad 0..3
    const int l16  = lane & 15;
    const int i0   = ib * 32;

    // A-fragments: A[m=l16][k=q*8+j] per 16x16x32 bf16 layout; k-chunk c covers 32 k.
    short8 A[2][4];
    #pragma unroll
    for (int t = 0; t < 2; ++t)
        #pragma unroll
        for (int c = 0; c < 4; ++c)
            A[t][c] = *(const short8*)(G + (i0 + 16 * t + l16) * ND + c * 32 + q * 8);

    // Classes of the 8 rows this lane accumulates (C/D layout: row=(q*4+r), col=l16).
    int pcls[8], ncls[8];
    #pragma unroll
    for (int t = 0; t < 2; ++t)
        #pragma unroll
        for (int r = 0; r < 4; ++r) {
            const int rc = cls[i0 + 16 * t + 4 * q + r];
            pcls[t * 4 + r] = rc ^ 1;
            ncls[t * 4 + r] = rc ^ 2;
        }

    float Ep[8], En[8], Ls[8];
    #pragma unroll
    for (int i = 0; i < 8; ++i) { Ep[i] = 0.f; En[i] = 0.f; Ls[i] = 0.f; }

    const int jt_end = jb * 128 + 128;
    for (int jt = jb * 128 + wave; jt < jt_end; jt += 4) {
        const int j0 = jt * 16;
        short8 Bf[4];
        #pragma unroll
        for (int c = 0; c < 4; ++c)
            Bf[c] = *(const short8*)(G + (j0 + l16) * ND + c * 32 + q * 8);
        const int cj = cls[j0 + l16];  // class of this lane's column

        #pragma unroll
        for (int t = 0; t < 2; ++t) {
            f32x4 acc = {0.f, 0.f, 0.f, 0.f};
            #pragma unroll
            for (int c = 0; c < 4; ++c)
                acc = __builtin_amdgcn_mfma_f32_16x16x32_bf16(A[t][c], Bf[c], acc, 0, 0, 0);
            #pragma unroll
            for (int r = 0; r < 4; ++r) {
                const float s = acc[r];                       // sim (cols differ in class -> diag excluded)
                const float e = fast_exp2(s * (TEMP_INV * LOG2E));  // exp(sim/T)
                const int idx = t * 4 + r;
                const bool p = (cj == pcls[idx]);
                const bool n = (cj == ncls[idx]);
                Ep[idx] += p ? e : 0.0f;
                Ls[idx] += p ? s : 0.0f;
                En[idx] += n ? e : 0.0f;
            }
        }
    }

    // Reduce across the 16 column-lanes (xor bits 0..3 stay inside the quad group).
    #pragma unroll
    for (int m = 1; m < 16; m <<= 1) {
        #pragma unroll
        for (int i = 0; i < 8; ++i) {
            Ep[i] += __shfl_xor(Ep[i], m, 64);
            En[i] += __shfl_xor(En[i], m, 64);
            Ls[i] += __shfl_xor(Ls[i], m, 64);
        }
    }
    if (l16 == 0) {
        #pragma unroll
        for (int t = 0; t < 2; ++t)
            #pragma unroll
            for (int r = 0; r < 4; ++r) {
                const int row = i0 + 16 * t + 4 * q + r;
                const int idx = t * 4 + r;
                atomicAdd(&EposG[row], Ep[idx]);
                atomicAdd(&EnegG[row], En[idx]);
                atomicAdd(&LsumG[row], Ls[idx]);
            }
    }
}

__global__ __launch_bounds__(256) void finalize_kernel(
    const float* __restrict__ EposG, const float* __restrict__ EnegG,
    const float* __restrict__ LsumG, const unsigned char* __restrict__ cls,
    const int* __restrict__ cnt, float* __restrict__ out)
{
    const int i = blockIdx.x * 256 + threadIdx.x;
    const int c = cls[i];
    const int pc = cnt[c ^ 1];
    const int nc = cnt[c ^ 2];
    float contrib = 0.0f;
    if (pc > 0 && nc > 0) {
        const float ld = logf(EposG[i] + EnegG[i]);
        const float mean = (TEMP_INV * LsumG[i] - (float)pc * ld) / (float)pc;
        contrib = -mean * (1.0f / (float)NB);
    }
    #pragma unroll
    for (int m = 1; m < 64; m <<= 1) contrib += __shfl_xor(contrib, m, 64);
    if ((threadIdx.x & 63) == 0) atomicAdd(out, contrib);
}

extern "C" void kernel_launch(void* const* d_in, const int* in_sizes, int n_in,
                              void* d_out, int out_size, void* d_ws, size_t ws_size,
                              hipStream_t stream) {
    const float* F  = (const float*)d_in[0];
    const int* dix  = (const int*)d_in[1];
    const int* tt   = (const int*)d_in[2];
    const int* tp   = (const int*)d_in[3];
    float* out = (float*)d_out;

    char* ws = (char*)d_ws;
    unsigned short* G   = (unsigned short*)(ws + OFF_G);
    float* EposG        = (float*)(ws + OFF_EPOS);
    float* EnegG        = (float*)(ws + OFF_ENEG);
    float* LsumG        = (float*)(ws + OFF_LSUM);
    unsigned char* cls  = (unsigned char*)(ws + OFF_CLS);
    int* cnt            = (int*)(ws + OFF_CNT);

    hipMemsetAsync(ws + ZERO_BEG, 0, ZERO_SZ, stream);
    hipMemsetAsync(d_out, 0, sizeof(float), stream);
    prep_kernel<<<NB, 64, 0, stream>>>(F, dix, tt, tp, G, cls, cnt);
    sim_kernel<<<1024, 256, 0, stream>>>(G, cls, EposG, EnegG, LsumG);
    finalize_kernel<<<NB / 256, 256, 0, stream>>>(EposG, EnegG, LsumG, cls, cnt, out);
}

// Round 2
// 138.132 us; speedup vs baseline: 1.6516x; 1.6516x over previous
//
#include <hip/hip_runtime.h>

// ContrastiveLoss: B=8192, D=128, T=0.1, SINGLE_POS=False.
// Classes c = 2*tt + tp in {0..3}; pos class = c^1, neg class = c^2.
// loss = -(1/B) * sum_i [valid_i * (10*Lpos_i - pos_cnt_i*log(Epos_i+Eneg_i)) / pos_cnt_i]

#define NB 8192
#define ND 128
#define TEMP_INV 10.0f
#define LOG2E 1.4426950408889634f
#define EXPK (TEMP_INV * LOG2E)

#define ITILE 128            // rows per sim block
#define NIB (NB / ITILE)     // 64 i-blocks
#define JSPLIT 16            // j-ranges (512 cols each)

typedef __attribute__((ext_vector_type(8))) short short8;
typedef __attribute__((ext_vector_type(4))) float f32x4;

// ws layout (bytes)
#define OFF_G    0                       // 8192*128 bf16 = 2 MB
#define OFF_EPP  (2*1024*1024)           // 16*8192 f32 = 512 KB
#define OFF_ENP  (OFF_EPP + 512*1024)    // 512 KB
#define OFF_LSP  (OFF_ENP + 512*1024)    // 512 KB
#define OFF_CLS  (OFF_LSP + 512*1024)    // 8192 u8
#define OFF_CNTP (OFF_CLS + 8192)        // 16 i32 (4 hist blocks x 4 classes)

__device__ __forceinline__ unsigned short f2bf(float x) {
    unsigned int u = __float_as_uint(x);
    unsigned int r = (u + 0x7FFFu + ((u >> 16) & 1u)) >> 16;  // RNE
    return (unsigned short)r;
}

__device__ __forceinline__ float fast_exp2(float x) {
#if __has_builtin(__builtin_amdgcn_exp2f)
    return __builtin_amdgcn_exp2f(x);
#else
    return exp2f(x);
#endif
}

// Blocks 0..2047: normalize 4 rows each (wave per row), write bf16 G.
// Blocks 2048..2051: class gather + LDS histogram -> partial counts (NO global
// atomics — the 8192 same-address atomicAdds were 96 us last round).
// Block 2048 also zeroes d_out (replaces a hipMemsetAsync dispatch).
__global__ __launch_bounds__(256) void prep_kernel(
    const float* __restrict__ F, const int* __restrict__ dix,
    const int* __restrict__ tt, const int* __restrict__ tp,
    unsigned short* __restrict__ G, unsigned char* __restrict__ cls,
    int* __restrict__ cntP, float* __restrict__ out)
{
    if (blockIdx.x < 2048) {
        const int row  = blockIdx.x * 4 + (threadIdx.x >> 6);
        const int lane = threadIdx.x & 63;
        const float2 v = *(const float2*)(F + row * ND + lane * 2);
        float ss = v.x * v.x + v.y * v.y;
        #pragma unroll
        for (int m = 1; m < 64; m <<= 1) ss += __shfl_xor(ss, m, 64);
        const float inv = rsqrtf(fmaxf(ss, 1e-24f));
        ushort2 st;
        st.x = f2bf(v.x * inv);
        st.y = f2bf(v.y * inv);
        *(ushort2*)(G + row * ND + lane * 2) = st;
    } else {
        __shared__ int lh[4];
        const int h   = blockIdx.x - 2048;   // 0..3, 2048 rows each
        const int tid = threadIdx.x;
        if (tid < 4) lh[tid] = 0;
        __syncthreads();
        #pragma unroll
        for (int k = 0; k < 8; ++k) {
            const int row = h * 2048 + k * 256 + tid;
            const int ix  = dix[row];
            const int c   = ((tt[ix] & 1) << 1) | (tp[ix] & 1);
            cls[row] = (unsigned char)c;
            atomicAdd(&lh[c], 1);            // LDS atomic — cheap
        }
        __syncthreads();
        if (tid < 4) cntP[h * 4 + tid] = lh[tid];
        if (h == 0 && tid == 4) *out = 0.0f;
    }
}

// Grid: 1024 blocks = 64 i-tiles (128 rows) x 16 j-ranges (512 cols).
// 4 waves split the i dimension (32 rows each) and walk the SAME jt sequence,
// so B-fragment loads hit L1 for 3 of the 4 waves (L2 traffic 512->128 MB).
// Epilogue writes per-(row, j-range) partials — no global atomics.
__global__ __launch_bounds__(256) void sim_kernel(
    const unsigned short* __restrict__ G,
    const unsigned char* __restrict__ cls,
    float* __restrict__ EpP, float* __restrict__ EnP, float* __restrict__ LsP)
{
    const int ib   = blockIdx.x & (NIB - 1);
    const int jb   = blockIdx.x / NIB;       // 0..15
    const int wave = threadIdx.x >> 6;
    const int lane = threadIdx.x & 63;
    const int q    = lane >> 4;              // quad 0..3
    const int l16  = lane & 15;
    const int ri   = ib * ITILE + wave * 32; // this wave's 32 rows

    // A-fragments for 32 rows: A[m=l16][k=q*8+j], k-chunk c covers 32 k.
    short8 A[2][4];
    #pragma unroll
    for (int t = 0; t < 2; ++t)
        #pragma unroll
        for (int c = 0; c < 4; ++c)
            A[t][c] = *(const short8*)(G + (ri + 16 * t + l16) * ND + c * 32 + q * 8);

    // C/D layout: row = 16t + 4q + r, col = l16.
    int pcls[8], ncls[8];
    #pragma unroll
    for (int t = 0; t < 2; ++t)
        #pragma unroll
        for (int r = 0; r < 4; ++r) {
            const int rc = cls[ri + 16 * t + 4 * q + r];
            pcls[t * 4 + r] = rc ^ 1;
            ncls[t * 4 + r] = rc ^ 2;
        }

    float Ep[8], En[8], Ls[8];
    #pragma unroll
    for (int i = 0; i < 8; ++i) { Ep[i] = 0.f; En[i] = 0.f; Ls[i] = 0.f; }

    const int jt0 = jb * 32;
    for (int k = 0; k < 32; ++k) {
        const int j0 = (jt0 + k) * 16;
        short8 Bf[4];
        #pragma unroll
        for (int c = 0; c < 4; ++c)
            Bf[c] = *(const short8*)(G + (j0 + l16) * ND + c * 32 + q * 8);
        const int cj = cls[j0 + l16];        // class of this lane's column

        #pragma unroll
        for (int t = 0; t < 2; ++t) {
            f32x4 acc = {0.f, 0.f, 0.f, 0.f};
            #pragma unroll
            for (int c = 0; c < 4; ++c)
                acc = __builtin_amdgcn_mfma_f32_16x16x32_bf16(A[t][c], Bf[c], acc, 0, 0, 0);
            #pragma unroll
            for (int r = 0; r < 4; ++r) {
                const float s = acc[r];       // cols with equal class never count -> diag excluded
                const float e = fast_exp2(s * EXPK);
                const int idx = t * 4 + r;
                const bool p = (cj == pcls[idx]);
                const bool n = (cj == ncls[idx]);
                Ep[idx] += p ? e : 0.0f;
                Ls[idx] += p ? s : 0.0f;
                En[idx] += n ? e : 0.0f;
            }
        }
    }

    // Reduce across the 16 column-lanes (xor bits 0..3 stay in the 16-group).
    #pragma unroll
    for (int m = 1; m < 16; m <<= 1) {
        #pragma unroll
        for (int i = 0; i < 8; ++i) {
            Ep[i] += __shfl_xor(Ep[i], m, 64);
            En[i] += __shfl_xor(En[i], m, 64);
            Ls[i] += __shfl_xor(Ls[i], m, 64);
        }
    }
    if (l16 == 0) {
        #pragma unroll
        for (int t = 0; t < 2; ++t)
            #pragma unroll
            for (int r = 0; r < 4; ++r) {
                const int row = ri + 16 * t + 4 * q + r;
                const int idx = t * 4 + r;
                EpP[jb * NB + row] = Ep[idx];   // plain stores, unique writer
                EnP[jb * NB + row] = En[idx];
                LsP[jb * NB + row] = Ls[idx];
            }
    }
}

__global__ __launch_bounds__(256) void finalize_kernel(
    const float* __restrict__ EpP, const float* __restrict__ EnP,
    const float* __restrict__ LsP, const unsigned char* __restrict__ cls,
    const int* __restrict__ cntP, float* __restrict__ out)
{
    const int i = blockIdx.x * 256 + threadIdx.x;
    const int c = cls[i];
    int pcnt = 0, ncnt = 0;
    #pragma unroll
    for (int h = 0; h < 4; ++h) {
        pcnt += cntP[h * 4 + (c ^ 1)];
        ncnt += cntP[h * 4 + (c ^ 2)];
    }
    float ep = 0.f, en = 0.f, ls = 0.f;
    #pragma unroll
    for (int jb = 0; jb < JSPLIT; ++jb) {
        ep += EpP[jb * NB + i];
        en += EnP[jb * NB + i];
        ls += LsP[jb * NB + i];
    }
    float contrib = 0.0f;
    if (pcnt > 0 && ncnt > 0) {
        const float ld = logf(ep + en);
        contrib = -(TEMP_INV * ls - (float)pcnt * ld) / ((float)pcnt * (float)NB);
    }
    #pragma unroll
    for (int m = 1; m < 64; m <<= 1) contrib += __shfl_xor(contrib, m, 64);
    __shared__ float wsum[4];
    if ((threadIdx.x & 63) == 0) wsum[threadIdx.x >> 6] = contrib;
    __syncthreads();
    if (threadIdx.x == 0)
        atomicAdd(out, wsum[0] + wsum[1] + wsum[2] + wsum[3]);
}

extern "C" void kernel_launch(void* const* d_in, const int* in_sizes, int n_in,
                              void* d_out, int out_size, void* d_ws, size_t ws_size,
                              hipStream_t stream) {
    const float* F  = (const float*)d_in[0];
    const int* dix  = (const int*)d_in[1];
    const int* tt   = (const int*)d_in[2];
    const int* tp   = (const int*)d_in[3];
    float* out = (float*)d_out;

    char* ws = (char*)d_ws;
    unsigned short* G  = (unsigned short*)(ws + OFF_G);
    float* EpP         = (float*)(ws + OFF_EPP);
    float* EnP         = (float*)(ws + OFF_ENP);
    float* LsP         = (float*)(ws + OFF_LSP);
    unsigned char* cls = (unsigned char*)(ws + OFF_CLS);
    int* cntP          = (int*)(ws + OFF_CNTP);

    prep_kernel<<<2052, 256, 0, stream>>>(F, dix, tt, tp, G, cls, cntP, out);
    sim_kernel<<<NIB * JSPLIT, 256, 0, stream>>>(G, cls, EpP, EnP, LsP);
    finalize_kernel<<<NB / 256, 256, 0, stream>>>(EpP, EnP, LsP, cls, cntP, out);
}